// Round 11
// baseline (532.249 us; speedup 1.0000x reference)
//
#include <hip/hip_runtime.h>

typedef __attribute__((ext_vector_type(4))) float f32x4;
typedef __attribute__((ext_vector_type(8))) __bf16 bf16x8;
typedef __attribute__((ext_vector_type(8))) unsigned short u16x8;
typedef __attribute__((ext_vector_type(4))) unsigned short u16x4;
typedef __attribute__((ext_vector_type(4))) short s16x4;
typedef unsigned short ushort_t;

// ---------- bf16 helpers ----------
__device__ __forceinline__ unsigned short f2bf(float x) {
  unsigned u = __builtin_bit_cast(unsigned, x);
  u += 0x7fffu + ((u >> 16) & 1u);
  return (unsigned short)(u >> 16);
}
__device__ __forceinline__ float bf2f(unsigned short h) {
  unsigned u = ((unsigned)h) << 16;
  return __builtin_bit_cast(float, u);
}
__device__ __forceinline__ short f2bf_n(float x) {
  return __builtin_bit_cast(short, (__bf16)x);
}

// ---------- async global->LDS (16B per lane) ----------
__device__ __forceinline__ void gload_lds16(const void* g, void* l) {
  __builtin_amdgcn_global_load_lds(
      (const __attribute__((address_space(1))) unsigned int*)g,
      (__attribute__((address_space(3))) unsigned int*)l, 16, 0, 0);
}

// ---------- f32 -> bf16 conversion ----------
__global__ __launch_bounds__(256) void k_f32_to_bf16(
    const float* __restrict__ src, ushort_t* __restrict__ dst, int n8) {
  int i = blockIdx.x * 256 + threadIdx.x;
  if (i >= n8) return;
  float4 a = ((const float4*)src)[i * 2 + 0];
  float4 b = ((const float4*)src)[i * 2 + 1];
  u16x8 o;
  o[0] = f2bf(a.x); o[1] = f2bf(a.y); o[2] = f2bf(a.z); o[3] = f2bf(a.w);
  o[4] = f2bf(b.x); o[5] = f2bf(b.y); o[6] = f2bf(b.z); o[7] = f2bf(b.w);
  ((u16x8*)dst)[i] = o;
}

// ---------- bf16 B^T GEMM: C[M,N] = A[M,K] * B[N,K]^T (m97 structure) ----------
// XCD-aware remap (T1): HW dispatch order round-robins consecutive ids over
// the 8 XCD L2s. We chunk a LOGICAL M-MAJOR index so each XCD owns a 4-tile
// A-row-stripe (4x128 rows x K x 2B = 4MB = one L2) and streams B through it.
// Both grids used here have nwg % 8 == 0, so chunking is exactly bijective.
// ROPE=1 (QKV): rotary fused in epilogue; pairs (d, d+32) are acc[m][n] /
// acc[m][n+2] of the same lane in the wc==0 waves.
template <int OUT_BF16, int ROPE>
__global__ __launch_bounds__(256, 2) void k_gemm_bt(
    const ushort_t* __restrict__ A, const ushort_t* __restrict__ B,
    void* __restrict__ C, int K, int lda, int ldb, int ldc,
    const int* __restrict__ pos_ids) {
  __shared__ ushort_t lA[128 * 64];
  __shared__ ushort_t lB[128 * 64];
  const int t = threadIdx.x;
  const int ln = t & 63, w = t >> 6;
  const int fr = ln & 15, fg = ln >> 4;
  // --- XCD chunked remap: orig (HW order) -> logical m-major index ---
  const int nwg = (int)(gridDim.x * gridDim.y);
  const int orig = (int)(blockIdx.y * gridDim.x + blockIdx.x);
  const int cpx = nwg >> 3;                 // blocks per XCD (nwg % 8 == 0)
  const int wg = (orig & 7) * cpx + (orig >> 3);
  const int m0 = (wg / (int)gridDim.y) * 128;   // m-major: A-stripe per chunk
  const int n0 = (wg % (int)gridDim.y) * 128;
  const int wr = (w >> 1) * 64, wc = (w & 1) * 64;

  const int srow = t >> 3;
  const int scol = ((((t & 7) * 16) ^ ((srow & 7) << 4)) >> 1);
  const ushort_t* pA = A + (srow + m0) * lda + scol;
  const ushort_t* pB = B + (srow + n0) * ldb + scol;
  char* lAb = (char*)lA + (w << 10);
  char* lBb = (char*)lB + (w << 10);

  f32x4 acc[4][4] = {};

  for (int k0 = 0; k0 < K; k0 += 64) {
    __syncthreads();
#pragma unroll
    for (int i = 0; i < 4; ++i) {
      gload_lds16(pA + i * 32 * lda + k0, lAb + i * 4096);
      gload_lds16(pB + i * 32 * ldb + k0, lBb + i * 4096);
    }
    __syncthreads();
#pragma unroll
    for (int kh = 0; kh < 2; ++kh) {
      bf16x8 af[4], bfv[4];
#pragma unroll
      for (int m = 0; m < 4; ++m) {
        int row = wr + m * 16 + fr;
        af[m] = *(const bf16x8*)((const char*)lA + row * 128 +
                                 ((kh * 64 + fg * 16) ^ ((row & 7) << 4)));
      }
#pragma unroll
      for (int n = 0; n < 4; ++n) {
        int row = wc + n * 16 + fr;
        bfv[n] = *(const bf16x8*)((const char*)lB + row * 128 +
                                  ((kh * 64 + fg * 16) ^ ((row & 7) << 4)));
      }
#pragma unroll
      for (int m = 0; m < 4; ++m)
#pragma unroll
        for (int n = 0; n < 4; ++n)
          acc[m][n] = __builtin_amdgcn_mfma_f32_16x16x32_bf16(
              af[m], bfv[n], acc[m][n], 0, 0, 0);
    }
  }

  // ---- fused RoPE (QKV epilogue only; wave-uniform predicate) ----
  if (ROPE) {
    if (n0 < 5120 && wc == 0) {
#pragma unroll
      for (int n = 0; n < 2; ++n) {
        const float fi = (float)(n * 16 + fr);          // freq index 0..31
        const float inv = exp2f(-fi * (13.287712379549449f / 32.0f));
#pragma unroll
        for (int m = 0; m < 4; ++m) {
          const int row = m0 + wr + m * 16 + fg * 4;
#pragma unroll
          for (int j = 0; j < 4; ++j) {
            const float ang = (float)pos_ids[row + j] * inv;
            float sn, cs;
            __sincosf(ang, &sn, &cs);
            const float x1 = acc[m][n][j], x2 = acc[m][n + 2][j];
            acc[m][n][j]     = x1 * cs - x2 * sn;
            acc[m][n + 2][j] = x2 * cs + x1 * sn;
          }
        }
      }
    }
  }

#pragma unroll
  for (int m = 0; m < 4; ++m)
#pragma unroll
    for (int n = 0; n < 4; ++n) {
      int row = m0 + wr + m * 16 + fg * 4;
      int col = n0 + wc + n * 16 + fr;
#pragma unroll
      for (int j = 0; j < 4; ++j) {
        if (OUT_BF16)
          ((ushort_t*)C)[(size_t)(row + j) * ldc + col] = f2bf(acc[m][n][j]);
        else
          ((float*)C)[(size_t)(row + j) * ldc + col] = acc[m][n][j];
      }
    }
}

// ---------- causal GQA flash attention (S^T / O^T, reg-resident P) ----------
// grid (16, 32, 2), 256 thr. NOTE: launch_bounds min-waves MUST stay at 2 —
// requesting 4 forces the 64-VGPR allocation step and the accumulator state
// spills to scratch (R3: FETCH 70MB->668MB, 254us->413us).
// T14 async-STAGE: V(kt+1) global->reg loads issued after K gload_lds (order
// pinned both sides); staging barrier = counted vmcnt(4). Measured neutral
// (R10) but correct; kept.
__global__ __launch_bounds__(256, 2) void k_attn(
    const ushort_t* __restrict__ QKV, ushort_t* __restrict__ O) {
  __shared__ ushort_t lK[64 * 128];     // XOR-swizzled rows of 256B
  __shared__ ushort_t lV[16 * 96 * 4];  // quad layout [k4][c ^ (k4&15)][kr]

  const int t = threadIdx.x, ln = t & 63, w = t >> 6;
  const int fr = ln & 15, fg = ln >> 4;
  const int h = blockIdx.y, b = blockIdx.z;
  // co-resident blocks differ by 256 in id -> h differs by 16: pair qt with
  // 15-qt via (h>>4)&1 so each CU's resident blocks sum to uniform work.
  const int qt = ((h >> 4) & 1) ? (15 - (int)blockIdx.x) : (int)blockIdx.x;
  const int hk = h >> 2;
  const int q0 = qt * 128 + w * 32;
  const int tb = b * 2048;

  // Q B-frags: lane (fr,fg) holds Q[q0+rq*16+fr][kb*32+fg*8 ..+7]
  bf16x8 qf[2][4];
#pragma unroll
  for (int rq = 0; rq < 2; ++rq)
#pragma unroll
    for (int kb = 0; kb < 4; ++kb)
      qf[rq][kb] = *(const bf16x8*)(QKV +
                    (size_t)(tb + q0 + rq * 16 + fr) * 5888 + h * 128 +
                    kb * 32 + fg * 8);

  f32x4 oacc[6][2] = {};            // O^T: c = c6*16+fg*4+j, q = rq*16+fr
  float mreg[2] = {-1e30f, -1e30f};
  float lreg[2] = {0.f, 0.f};

  const int krow = t >> 4;
  const int kse = ((((t & 15) * 16) ^ (((t >> 4) & 7) << 4)) >> 1);
  const int k4s = t / 12, c8s = t % 12;       // V staging unit (t<192)

  const float sc = 0.088388347648318447f;     // 1/sqrt(128)
  const float l2e = 1.4426950408889634f;
  const float scl2e = sc * l2e;

  // ---- initial V prefetch (tile 0) ----
  u16x8 vrow[4];
  const ushort_t* pVb =
      QKV + (size_t)(tb + k4s * 4) * 5888 + 5120 + hk * 96 + c8s * 8;
  if (t < 192) {
#pragma unroll
    for (int kr = 0; kr < 4; ++kr)
      vrow[kr] = *(const u16x8*)(pVb + (size_t)kr * 5888);
  }

  const int nkt = (qt + 1) * 2;
  for (int kt = 0; kt < nkt; ++kt) {
    const int kb0 = kt * 64;
    __syncthreads();
    // ---- V(kt): regs -> quad-layout LDS ----
    if (t < 192) {
#pragma unroll
      for (int i = 0; i < 8; ++i) {
        int cs = (c8s * 8 + i) ^ (k4s & 15);
        u16x4 q;
#pragma unroll
        for (int kr = 0; kr < 4; ++kr) q[kr] = vrow[kr][i];
        *(u16x4*)(&lV[(k4s * 96 + cs) * 4]) = q;
      }
    }
    // ---- K(kt): async gload -> lK (swizzled); MUST issue before V loads ----
    {
      const ushort_t* pK =
          QKV + (size_t)(tb + kb0 + krow) * 5888 + 4096 + hk * 128 + kse;
#pragma unroll
      for (int i = 0; i < 4; ++i)
        gload_lds16(pK + (size_t)i * 16 * 5888,
                    (char*)lK + i * 4096 + (w << 10));
    }
    __builtin_amdgcn_sched_barrier(0);   // pin: K issues older than V issues
    // ---- V(kt+1) prefetch issue (latency hides under this tile's compute) --
    const bool pre = (kt + 1 < nkt);
    if (pre && t < 192) {
      const ushort_t* pV = pVb + (size_t)(kb0 + 64) * 5888;
#pragma unroll
      for (int kr = 0; kr < 4; ++kr)
        vrow[kr] = *(const u16x8*)(pV + (size_t)kr * 5888);
    }
    __builtin_amdgcn_sched_barrier(0);   // pin: V issues before the wait
    // ---- staging barrier: counted vmcnt keeps V(kt+1) in flight ----
    if (pre && w < 3)
      asm volatile("s_waitcnt vmcnt(4) lgkmcnt(0)" ::: "memory");
    else
      asm volatile("s_waitcnt vmcnt(0) lgkmcnt(0)" ::: "memory");
    __builtin_amdgcn_s_barrier();
    asm volatile("" ::: "memory");
    __builtin_amdgcn_sched_barrier(0);

    if (kb0 > q0 + 31) continue;   // wave fully masked for this tile
    // ---- S^T = K Q^T ----
    f32x4 s[4][2] = {};
    __builtin_amdgcn_s_setprio(1);
#pragma unroll
    for (int cb = 0; cb < 4; ++cb) {
      const int kv = cb * 16 + fr;
      bf16x8 kf[4];
#pragma unroll
      for (int kb = 0; kb < 4; ++kb)
        kf[kb] = *(const bf16x8*)((const char*)lK + kv * 256 +
                                  ((kb * 64 + fg * 16) ^ ((kv & 7) << 4)));
#pragma unroll
      for (int rq = 0; rq < 2; ++rq)
#pragma unroll
        for (int kb = 0; kb < 4; ++kb)
          s[cb][rq] = __builtin_amdgcn_mfma_f32_16x16x32_bf16(
              kf[kb], qf[rq][kb], s[cb][rq], 0, 0, 0);
    }
    __builtin_amdgcn_s_setprio(0);
    // ---- mask (only partial tiles; wave-uniform branch) ----
    if (kb0 + 63 > q0) {
#pragma unroll
      for (int rq = 0; rq < 2; ++rq) {
        const int qrel = q0 + rq * 16 + fr - kb0;
#pragma unroll
        for (int cb = 0; cb < 4; ++cb)
#pragma unroll
          for (int j = 0; j < 4; ++j)
            if (cb * 16 + fg * 4 + j > qrel) s[cb][rq][j] = -3.0e38f;
      }
    }
    // ---- online softmax (raw-domain max, sc folded into exp) ----
    float pmax[2];
#pragma unroll
    for (int rq = 0; rq < 2; ++rq) {
      f32x4 rm4 = s[0][rq];
#pragma unroll
      for (int cb = 1; cb < 4; ++cb)
#pragma unroll
        for (int j = 0; j < 4; ++j) rm4[j] = fmaxf(rm4[j], s[cb][rq][j]);
      float rm = fmaxf(fmaxf(rm4[0], rm4[1]), fmaxf(rm4[2], rm4[3]));
      rm = fmaxf(rm, __shfl_xor(rm, 16, 64));
      rm = fmaxf(rm, __shfl_xor(rm, 32, 64));
      pmax[rq] = rm * sc;
    }
    // defer-max (T13): rescale only when the running max grows by > 6
    bool need = (pmax[0] > mreg[0] + 6.f) || (pmax[1] > mreg[1] + 6.f);
    if (__any(need)) {
#pragma unroll
      for (int rq = 0; rq < 2; ++rq) {
        float mnew = fmaxf(mreg[rq], pmax[rq]);
        float sf = exp2f((mreg[rq] - mnew) * l2e);
        mreg[rq] = mnew;
        lreg[rq] *= sf;
#pragma unroll
        for (int c6 = 0; c6 < 6; ++c6) oacc[c6][rq] *= sf;
      }
    }
    s16x4 pb[4][2];
#pragma unroll
    for (int rq = 0; rq < 2; ++rq) {
      const float mb = mreg[rq] * l2e;
      f32x4 ps4 = {};
#pragma unroll
      for (int cb = 0; cb < 4; ++cb) {
#pragma unroll
        for (int j = 0; j < 4; ++j) {
          float p = exp2f(fmaf(s[cb][rq][j], scl2e, -mb));
          s[cb][rq][j] = p;
          ps4[j] += p;
        }
      }
      float ps = (ps4[0] + ps4[1]) + (ps4[2] + ps4[3]);
      ps += __shfl_xor(ps, 16, 64);
      ps += __shfl_xor(ps, 32, 64);
      lreg[rq] += ps;
      // pack P -> bf16 frags (lane-local)
#pragma unroll
      for (int cb = 0; cb < 4; ++cb) {
        s16x4 v;
#pragma unroll
        for (int j = 0; j < 4; ++j) v[j] = f2bf_n(s[cb][rq][j]);
        pb[cb][rq] = v;
      }
    }
    // ---- O^T += V^T P (A-frag from quad-layout lV, B-frag in regs) ----
    __builtin_amdgcn_s_setprio(1);
#pragma unroll
    for (int cb = 0; cb < 4; ++cb) {
      const int k4 = cb * 4 + fg;
      s16x4 va[6];
#pragma unroll
      for (int c6 = 0; c6 < 6; ++c6)
        va[c6] = *(const s16x4*)(
            &lV[(k4 * 96 + (((c6 * 16 + fr) ^ (k4 & 15)))) * 4]);
#pragma unroll
      for (int c6 = 0; c6 < 6; ++c6)
#pragma unroll
        for (int rq = 0; rq < 2; ++rq)
          oacc[c6][rq] = __builtin_amdgcn_mfma_f32_16x16x16bf16_1k(
              va[c6], pb[cb][rq], oacc[c6][rq], 0, 0, 0);
    }
    __builtin_amdgcn_s_setprio(0);
  }
  // ---- epilogue ----
#pragma unroll
  for (int rq = 0; rq < 2; ++rq) {
    const float inv = 1.0f / lreg[rq];
    const size_t rowb = (size_t)(tb + q0 + rq * 16 + fr) * 3072 + h * 96;
#pragma unroll
    for (int c6 = 0; c6 < 6; ++c6) {
      u16x4 o;
#pragma unroll
      for (int j = 0; j < 4; ++j)
        o[j] = (unsigned short)f2bf_n(oacc[c6][rq][j] * inv);
      *(u16x4*)(&O[rowb + c6 * 16 + fg * 4]) = o;
    }
  }
}

// ---------------- launcher ----------------
extern "C" void kernel_launch(void* const* d_in, const int* in_sizes, int n_in,
                              void* d_out, int out_size, void* d_ws,
                              size_t ws_size, hipStream_t stream) {
  const float* X  = (const float*)d_in[0];
  const int*   pos = (const int*)d_in[1];
  const float* Wq = (const float*)d_in[2];
  const float* Wk = (const float*)d_in[3];
  const float* Wv = (const float*)d_in[4];
  const float* Wo = (const float*)d_in[5];
  float* out = (float*)d_out;

  ushort_t* Xb    = (ushort_t*)d_ws;
  ushort_t* Wob   = Xb + 16777216;
  ushort_t* QKV   = Wob + 12582912;
  ushort_t* AO    = QKV + 24117248;
  ushort_t* Wqkvb = (ushort_t*)d_out;   // staged, consumed before O-proj

  k_f32_to_bf16<<<8192, 256, 0, stream>>>(X, Xb, 2097152);
  k_f32_to_bf16<<<8192, 256, 0, stream>>>(Wq, Wqkvb, 2097152);
  k_f32_to_bf16<<<2048, 256, 0, stream>>>(Wk, Wqkvb + 16777216, 524288);
  k_f32_to_bf16<<<1536, 256, 0, stream>>>(Wv, Wqkvb + 20971520, 393216);
  k_f32_to_bf16<<<6144, 256, 0, stream>>>(Wo, Wob, 1572864);

  // QKV projection + fused RoPE: (4096x4096)*(5888x4096)^T -> (4096x5888)
  k_gemm_bt<1, 1><<<dim3(32, 46), 256, 0, stream>>>(Xb, Wqkvb, QKV, 4096,
                                                    4096, 4096, 5888, pos);
  // causal GQA flash attention -> (4096 x 3072) bf16
  k_attn<<<dim3(16, 32, 2), 256, 0, stream>>>(QKV, AO);
  // output projection: (4096 x 3072) * (4096 x 3072)^T -> (4096 x 4096) f32
  k_gemm_bt<0, 0><<<dim3(32, 32), 256, 0, stream>>>(AO, Wob, out, 3072, 3072,
                                                    3072, 4096, nullptr);
}

// Round 12
// 478.196 us; speedup vs baseline: 1.1130x; 1.1130x over previous
//
#include <hip/hip_runtime.h>

typedef __attribute__((ext_vector_type(4))) float f32x4;
typedef __attribute__((ext_vector_type(8))) __bf16 bf16x8;
typedef __attribute__((ext_vector_type(8))) unsigned short u16x8;
typedef __attribute__((ext_vector_type(4))) unsigned short u16x4;
typedef __attribute__((ext_vector_type(4))) short s16x4;
typedef unsigned short ushort_t;

// ---------- bf16 helpers ----------
__device__ __forceinline__ unsigned short f2bf(float x) {
  unsigned u = __builtin_bit_cast(unsigned, x);
  u += 0x7fffu + ((u >> 16) & 1u);
  return (unsigned short)(u >> 16);
}
__device__ __forceinline__ float bf2f(unsigned short h) {
  unsigned u = ((unsigned)h) << 16;
  return __builtin_bit_cast(float, u);
}
__device__ __forceinline__ short f2bf_n(float x) {
  return __builtin_bit_cast(short, (__bf16)x);
}

// ---------- async global->LDS (16B per lane) ----------
__device__ __forceinline__ void gload_lds16(const void* g, void* l) {
  __builtin_amdgcn_global_load_lds(
      (const __attribute__((address_space(1))) unsigned int*)g,
      (__attribute__((address_space(3))) unsigned int*)l, 16, 0, 0);
}

// ---------- f32 -> bf16 conversion ----------
__global__ __launch_bounds__(256) void k_f32_to_bf16(
    const float* __restrict__ src, ushort_t* __restrict__ dst, int n8) {
  int i = blockIdx.x * 256 + threadIdx.x;
  if (i >= n8) return;
  float4 a = ((const float4*)src)[i * 2 + 0];
  float4 b = ((const float4*)src)[i * 2 + 1];
  u16x8 o;
  o[0] = f2bf(a.x); o[1] = f2bf(a.y); o[2] = f2bf(a.z); o[3] = f2bf(a.w);
  o[4] = f2bf(b.x); o[5] = f2bf(b.y); o[6] = f2bf(b.z); o[7] = f2bf(b.w);
  ((u16x8*)dst)[i] = o;
}

// ---------- bf16 B^T GEMM: C[M,N] = A[M,K] * B[N,K]^T (m97 structure) ----------
// Default block mapping (R11 lesson: gridDim.x % 8 == 0 makes HW dispatch
// already XCD-stripe A optimally; explicit remap doubled FETCH_SIZE).
// ROPE=1 (QKV): rotary fused in epilogue; pairs (d, d+32) are acc[m][n] /
// acc[m][n+2] of the same lane in the wc==0 waves.
template <int OUT_BF16, int ROPE>
__global__ __launch_bounds__(256, 2) void k_gemm_bt(
    const ushort_t* __restrict__ A, const ushort_t* __restrict__ B,
    void* __restrict__ C, int K, int lda, int ldb, int ldc,
    const int* __restrict__ pos_ids) {
  __shared__ ushort_t lA[128 * 64];
  __shared__ ushort_t lB[128 * 64];
  const int t = threadIdx.x;
  const int ln = t & 63, w = t >> 6;
  const int fr = ln & 15, fg = ln >> 4;
  const int m0 = blockIdx.x * 128, n0 = blockIdx.y * 128;
  const int wr = (w >> 1) * 64, wc = (w & 1) * 64;

  const int srow = t >> 3;
  const int scol = ((((t & 7) * 16) ^ ((srow & 7) << 4)) >> 1);
  const ushort_t* pA = A + (srow + m0) * lda + scol;
  const ushort_t* pB = B + (srow + n0) * ldb + scol;
  char* lAb = (char*)lA + (w << 10);
  char* lBb = (char*)lB + (w << 10);

  f32x4 acc[4][4] = {};

  for (int k0 = 0; k0 < K; k0 += 64) {
    __syncthreads();
#pragma unroll
    for (int i = 0; i < 4; ++i) {
      gload_lds16(pA + i * 32 * lda + k0, lAb + i * 4096);
      gload_lds16(pB + i * 32 * ldb + k0, lBb + i * 4096);
    }
    __syncthreads();
#pragma unroll
    for (int kh = 0; kh < 2; ++kh) {
      bf16x8 af[4], bfv[4];
#pragma unroll
      for (int m = 0; m < 4; ++m) {
        int row = wr + m * 16 + fr;
        af[m] = *(const bf16x8*)((const char*)lA + row * 128 +
                                 ((kh * 64 + fg * 16) ^ ((row & 7) << 4)));
      }
#pragma unroll
      for (int n = 0; n < 4; ++n) {
        int row = wc + n * 16 + fr;
        bfv[n] = *(const bf16x8*)((const char*)lB + row * 128 +
                                  ((kh * 64 + fg * 16) ^ ((row & 7) << 4)));
      }
#pragma unroll
      for (int m = 0; m < 4; ++m)
#pragma unroll
        for (int n = 0; n < 4; ++n)
          acc[m][n] = __builtin_amdgcn_mfma_f32_16x16x32_bf16(
              af[m], bfv[n], acc[m][n], 0, 0, 0);
    }
  }

  // ---- fused RoPE (QKV epilogue only; wave-uniform predicate) ----
  if (ROPE) {
    if (n0 < 5120 && wc == 0) {
#pragma unroll
      for (int n = 0; n < 2; ++n) {
        const float fi = (float)(n * 16 + fr);          // freq index 0..31
        const float inv = exp2f(-fi * (13.287712379549449f / 32.0f));
#pragma unroll
        for (int m = 0; m < 4; ++m) {
          const int row = m0 + wr + m * 16 + fg * 4;
#pragma unroll
          for (int j = 0; j < 4; ++j) {
            const float ang = (float)pos_ids[row + j] * inv;
            float sn, cs;
            __sincosf(ang, &sn, &cs);
            const float x1 = acc[m][n][j], x2 = acc[m][n + 2][j];
            acc[m][n][j]     = x1 * cs - x2 * sn;
            acc[m][n + 2][j] = x2 * cs + x1 * sn;
          }
        }
      }
    }
  }

#pragma unroll
  for (int m = 0; m < 4; ++m)
#pragma unroll
    for (int n = 0; n < 4; ++n) {
      int row = m0 + wr + m * 16 + fg * 4;
      int col = n0 + wc + n * 16 + fr;
#pragma unroll
      for (int j = 0; j < 4; ++j) {
        if (OUT_BF16)
          ((ushort_t*)C)[(size_t)(row + j) * ldc + col] = f2bf(acc[m][n][j]);
        else
          ((float*)C)[(size_t)(row + j) * ldc + col] = acc[m][n][j];
      }
    }
}

// ---------- causal GQA flash attention (S^T / O^T, reg-resident P) ----------
// 8 waves / 256 q-rows per block: halves K/V staging phases + barriers vs the
// 4-wave version while per-wave state (VGPR) is unchanged. grid (8, 32, 2),
// 512 thr, 2 blocks/CU. Load balance: co-resident pair {id, id+256} = same
// (qt,h) at b=0/1 -> pair qt with 7-qt via b (36 tiles per pair, uniform).
// T14 async-STAGE kept: V(kt+1) loads issued after K gload_lds (order pinned);
// staging barrier = counted vmcnt(4) for the V-loading waves (w<3 <=> t<192).
__global__ __launch_bounds__(512, 2) void k_attn(
    const ushort_t* __restrict__ QKV, ushort_t* __restrict__ O) {
  __shared__ ushort_t lK[64 * 128];     // XOR-swizzled rows of 256B
  __shared__ ushort_t lV[16 * 96 * 4];  // quad layout [k4][c ^ (k4&15)][kr]

  const int t = threadIdx.x, ln = t & 63, w = t >> 6;
  const int fr = ln & 15, fg = ln >> 4;
  const int h = blockIdx.y, b = blockIdx.z;
  const int qt = b ? (7 - (int)blockIdx.x) : (int)blockIdx.x;
  const int hk = h >> 2;
  const int q0 = qt * 256 + w * 32;
  const int tb = b * 2048;

  // Q B-frags: lane (fr,fg) holds Q[q0+rq*16+fr][kb*32+fg*8 ..+7]
  bf16x8 qf[2][4];
#pragma unroll
  for (int rq = 0; rq < 2; ++rq)
#pragma unroll
    for (int kb = 0; kb < 4; ++kb)
      qf[rq][kb] = *(const bf16x8*)(QKV +
                    (size_t)(tb + q0 + rq * 16 + fr) * 5888 + h * 128 +
                    kb * 32 + fg * 8);

  f32x4 oacc[6][2] = {};            // O^T: c = c6*16+fg*4+j, q = rq*16+fr
  float mreg[2] = {-1e30f, -1e30f};
  float lreg[2] = {0.f, 0.f};

  const int krow = t >> 4;                    // 0..31 (2 issues x 32 rows)
  const int kse = ((((t & 15) * 16) ^ (((t >> 4) & 7) << 4)) >> 1);
  const int k4s = t / 12, c8s = t % 12;       // V staging unit (t<192)

  const float sc = 0.088388347648318447f;     // 1/sqrt(128)
  const float l2e = 1.4426950408889634f;
  const float scl2e = sc * l2e;

  // ---- initial V prefetch (tile 0) ----
  u16x8 vrow[4];
  const ushort_t* pVb =
      QKV + (size_t)(tb + k4s * 4) * 5888 + 5120 + hk * 96 + c8s * 8;
  if (t < 192) {
#pragma unroll
    for (int kr = 0; kr < 4; ++kr)
      vrow[kr] = *(const u16x8*)(pVb + (size_t)kr * 5888);
  }

  const int nkt = qt * 4 + 4;
  for (int kt = 0; kt < nkt; ++kt) {
    const int kb0 = kt * 64;
    __syncthreads();
    // ---- V(kt): regs -> quad-layout LDS ----
    if (t < 192) {
#pragma unroll
      for (int i = 0; i < 8; ++i) {
        int cs = (c8s * 8 + i) ^ (k4s & 15);
        u16x4 q;
#pragma unroll
        for (int kr = 0; kr < 4; ++kr) q[kr] = vrow[kr][i];
        *(u16x4*)(&lV[(k4s * 96 + cs) * 4]) = q;
      }
    }
    // ---- K(kt): async gload -> lK (swizzled); 2 issues x 32 rows ----
    {
      const ushort_t* pK =
          QKV + (size_t)(tb + kb0 + krow) * 5888 + 4096 + hk * 128 + kse;
#pragma unroll
      for (int i = 0; i < 2; ++i)
        gload_lds16(pK + (size_t)i * 32 * 5888,
                    (char*)lK + i * 8192 + (w << 10));
    }
    __builtin_amdgcn_sched_barrier(0);   // pin: K issues older than V issues
    // ---- V(kt+1) prefetch issue (latency hides under this tile's compute) --
    const bool pre = (kt + 1 < nkt);
    if (pre && t < 192) {
      const ushort_t* pV = pVb + (size_t)(kb0 + 64) * 5888;
#pragma unroll
      for (int kr = 0; kr < 4; ++kr)
        vrow[kr] = *(const u16x8*)(pV + (size_t)kr * 5888);
    }
    __builtin_amdgcn_sched_barrier(0);   // pin: V issues before the wait
    // ---- staging barrier: counted vmcnt keeps V(kt+1) in flight ----
    if (pre && w < 3)
      asm volatile("s_waitcnt vmcnt(4) lgkmcnt(0)" ::: "memory");
    else
      asm volatile("s_waitcnt vmcnt(0) lgkmcnt(0)" ::: "memory");
    __builtin_amdgcn_s_barrier();
    asm volatile("" ::: "memory");
    __builtin_amdgcn_sched_barrier(0);

    if (kb0 > q0 + 31) continue;   // wave fully masked for this tile
    // ---- S^T = K Q^T ----
    f32x4 s[4][2] = {};
    __builtin_amdgcn_s_setprio(1);
#pragma unroll
    for (int cb = 0; cb < 4; ++cb) {
      const int kv = cb * 16 + fr;
      bf16x8 kf[4];
#pragma unroll
      for (int kb = 0; kb < 4; ++kb)
        kf[kb] = *(const bf16x8*)((const char*)lK + kv * 256 +
                                  ((kb * 64 + fg * 16) ^ ((kv & 7) << 4)));
#pragma unroll
      for (int rq = 0; rq < 2; ++rq)
#pragma unroll
        for (int kb = 0; kb < 4; ++kb)
          s[cb][rq] = __builtin_amdgcn_mfma_f32_16x16x32_bf16(
              kf[kb], qf[rq][kb], s[cb][rq], 0, 0, 0);
    }
    __builtin_amdgcn_s_setprio(0);
    // ---- mask (only partial tiles; wave-uniform branch) ----
    if (kb0 + 63 > q0) {
#pragma unroll
      for (int rq = 0; rq < 2; ++rq) {
        const int qrel = q0 + rq * 16 + fr - kb0;
#pragma unroll
        for (int cb = 0; cb < 4; ++cb)
#pragma unroll
          for (int j = 0; j < 4; ++j)
            if (cb * 16 + fg * 4 + j > qrel) s[cb][rq][j] = -3.0e38f;
      }
    }
    // ---- online softmax (raw-domain max, sc folded into exp) ----
    float pmax[2];
#pragma unroll
    for (int rq = 0; rq < 2; ++rq) {
      f32x4 rm4 = s[0][rq];
#pragma unroll
      for (int cb = 1; cb < 4; ++cb)
#pragma unroll
        for (int j = 0; j < 4; ++j) rm4[j] = fmaxf(rm4[j], s[cb][rq][j]);
      float rm = fmaxf(fmaxf(rm4[0], rm4[1]), fmaxf(rm4[2], rm4[3]));
      rm = fmaxf(rm, __shfl_xor(rm, 16, 64));
      rm = fmaxf(rm, __shfl_xor(rm, 32, 64));
      pmax[rq] = rm * sc;
    }
    // defer-max (T13): rescale only when the running max grows by > 6
    bool need = (pmax[0] > mreg[0] + 6.f) || (pmax[1] > mreg[1] + 6.f);
    if (__any(need)) {
#pragma unroll
      for (int rq = 0; rq < 2; ++rq) {
        float mnew = fmaxf(mreg[rq], pmax[rq]);
        float sf = exp2f((mreg[rq] - mnew) * l2e);
        mreg[rq] = mnew;
        lreg[rq] *= sf;
#pragma unroll
        for (int c6 = 0; c6 < 6; ++c6) oacc[c6][rq] *= sf;
      }
    }
    s16x4 pb[4][2];
#pragma unroll
    for (int rq = 0; rq < 2; ++rq) {
      const float mb = mreg[rq] * l2e;
      f32x4 ps4 = {};
#pragma unroll
      for (int cb = 0; cb < 4; ++cb) {
#pragma unroll
        for (int j = 0; j < 4; ++j) {
          float p = exp2f(fmaf(s[cb][rq][j], scl2e, -mb));
          s[cb][rq][j] = p;
          ps4[j] += p;
        }
      }
      float ps = (ps4[0] + ps4[1]) + (ps4[2] + ps4[3]);
      ps += __shfl_xor(ps, 16, 64);
      ps += __shfl_xor(ps, 32, 64);
      lreg[rq] += ps;
      // pack P -> bf16 frags (lane-local)
#pragma unroll
      for (int cb = 0; cb < 4; ++cb) {
        s16x4 v;
#pragma unroll
        for (int j = 0; j < 4; ++j) v[j] = f2bf_n(s[cb][rq][j]);
        pb[cb][rq] = v;
      }
    }
    // ---- O^T += V^T P (A-frag from quad-layout lV, B-frag in regs) ----
    __builtin_amdgcn_s_setprio(1);
#pragma unroll
    for (int cb = 0; cb < 4; ++cb) {
      const int k4 = cb * 4 + fg;
      s16x4 va[6];
#pragma unroll
      for (int c6 = 0; c6 < 6; ++c6)
        va[c6] = *(const s16x4*)(
            &lV[(k4 * 96 + (((c6 * 16 + fr) ^ (k4 & 15)))) * 4]);
#pragma unroll
      for (int c6 = 0; c6 < 6; ++c6)
#pragma unroll
        for (int rq = 0; rq < 2; ++rq)
          oacc[c6][rq] = __builtin_amdgcn_mfma_f32_16x16x16bf16_1k(
              va[c6], pb[cb][rq], oacc[c6][rq], 0, 0, 0);
    }
    __builtin_amdgcn_s_setprio(0);
  }
  // ---- epilogue ----
#pragma unroll
  for (int rq = 0; rq < 2; ++rq) {
    const float inv = 1.0f / lreg[rq];
    const size_t rowb = (size_t)(tb + q0 + rq * 16 + fr) * 3072 + h * 96;
#pragma unroll
    for (int c6 = 0; c6 < 6; ++c6) {
      u16x4 o;
#pragma unroll
      for (int j = 0; j < 4; ++j)
        o[j] = (unsigned short)f2bf_n(oacc[c6][rq][j] * inv);
      *(u16x4*)(&O[rowb + c6 * 16 + fg * 4]) = o;
    }
  }
}

// ---------------- launcher ----------------
extern "C" void kernel_launch(void* const* d_in, const int* in_sizes, int n_in,
                              void* d_out, int out_size, void* d_ws,
                              size_t ws_size, hipStream_t stream) {
  const float* X  = (const float*)d_in[0];
  const int*   pos = (const int*)d_in[1];
  const float* Wq = (const float*)d_in[2];
  const float* Wk = (const float*)d_in[3];
  const float* Wv = (const float*)d_in[4];
  const float* Wo = (const float*)d_in[5];
  float* out = (float*)d_out;

  ushort_t* Xb    = (ushort_t*)d_ws;
  ushort_t* Wob   = Xb + 16777216;
  ushort_t* QKV   = Wob + 12582912;
  ushort_t* AO    = QKV + 24117248;
  ushort_t* Wqkvb = (ushort_t*)d_out;   // staged, consumed before O-proj

  k_f32_to_bf16<<<8192, 256, 0, stream>>>(X, Xb, 2097152);
  k_f32_to_bf16<<<8192, 256, 0, stream>>>(Wq, Wqkvb, 2097152);
  k_f32_to_bf16<<<2048, 256, 0, stream>>>(Wk, Wqkvb + 16777216, 524288);
  k_f32_to_bf16<<<1536, 256, 0, stream>>>(Wv, Wqkvb + 20971520, 393216);
  k_f32_to_bf16<<<6144, 256, 0, stream>>>(Wo, Wob, 1572864);

  // QKV projection + fused RoPE: (4096x4096)*(5888x4096)^T -> (4096x5888)
  k_gemm_bt<1, 1><<<dim3(32, 46), 256, 0, stream>>>(Xb, Wqkvb, QKV, 4096,
                                                    4096, 4096, 5888, pos);
  // causal GQA flash attention -> (4096 x 3072) bf16
  k_attn<<<dim3(8, 32, 2), 512, 0, stream>>>(QKV, AO);
  // output projection: (4096 x 3072) * (4096 x 3072)^T -> (4096 x 4096) f32
  k_gemm_bt<0, 0><<<dim3(32, 32), 256, 0, stream>>>(AO, Wob, out, 3072, 3072,
                                                    3072, 4096, nullptr);
}